// Round 15
// baseline (331.727 us; speedup 1.0000x reference)
//
#include <hip/hip_runtime.h>

#define N_NODES 50000
#define N_EDGES 800000
#define D_HID   128
#define PAD_V   (N_NODES << 8)             // pad slot: byte offset of zero row N

typedef unsigned int uint;
typedef unsigned short ushort;
typedef __attribute__((ext_vector_type(8))) short short8;
typedef __attribute__((ext_vector_type(4))) float f32x4;

#define NB       196                       // dst buckets of 256 nodes
#define CAP      6144                      // per-bucket ebuf capacity
#define P1_BLOCKS 200
#define P1_CHUNK  4000                     // 200 * 4000 = 800000 exactly
#define OVF_CAP  1024

// ---------------- P1: partition edges into dst-range buckets ----------------
__global__ __launch_bounds__(256) void part_k(const int* __restrict__ src,
                                              const int* __restrict__ dst,
                                              int* __restrict__ bcur,
                                              int2* __restrict__ ebuf, int e) {
    __shared__ int hist[NB];
    __shared__ int base[NB];
    int tid = threadIdx.x;
    if (tid < NB) hist[tid] = 0;
    __syncthreads();

    int e0 = blockIdx.x * P1_CHUNK;
    int2 ed[16];
    bool val[16];
#pragma unroll
    for (int i = 0; i < 16; ++i) {
        int o = i * 256 + tid;
        int idx = e0 + o;
        val[i] = (o < P1_CHUNK) && (idx < e);
        if (val[i]) {
            ed[i] = make_int2(src[idx], dst[idx]);
            atomicAdd(&hist[ed[i].y >> 8], 1);
        }
    }
    __syncthreads();
    if (tid < NB && hist[tid] > 0) base[tid] = atomicAdd(&bcur[tid], hist[tid]);
    __syncthreads();
    if (tid < NB) hist[tid] = 0;
    __syncthreads();
#pragma unroll
    for (int i = 0; i < 16; ++i) {
        if (val[i]) {
            int bk = ed[i].y >> 8;
            int o  = base[bk] + atomicAdd(&hist[bk], 1);
            if (o < CAP) ebuf[(size_t)bk * CAP + o] = ed[i];
        }
    }
}

// ---------------- scan of per-bucket totals (bcur) -> boff, row_ptr[N] ----------------
__global__ void bscan196_k(const int* __restrict__ bcur, int* __restrict__ boff,
                           int* __restrict__ row_ptr_end) {
    __shared__ int s[256];
    int t = threadIdx.x;
    int v = (t < NB) ? bcur[t] : 0;
    s[t] = v;
    __syncthreads();
    for (int off = 1; off < 256; off <<= 1) {
        int u = (t >= off) ? s[t - off] : 0;
        __syncthreads();
        s[t] += u;
        __syncthreads();
    }
    if (t < NB) boff[t] = s[t] - v;        // exclusive
    if (t == 255) *row_ptr_end = s[255];   // total -> row_ptr[n]
}

// ---------------- merged CSR build: count+scan+scatter+packed dump+padded dump ----------------
// col  : packed CSR (src<<8), for overflow nodes
// col32: fixed-stride 32 windows (src<<8, PAD_V sentinel pads), for the main aggregate
__global__ __launch_bounds__(256) void csr2_k(const int2* __restrict__ ebuf,
                                              const int* __restrict__ bcnt,
                                              const int* __restrict__ boff,
                                              int* __restrict__ row_ptr,
                                              float* __restrict__ dis,
                                              int* __restrict__ col,
                                              int* __restrict__ col32,
                                              int* __restrict__ ovf,
                                              int* __restrict__ ovf_cnt, int n) {
    __shared__ int deg[256];
    __shared__ int loc[256];
    __shared__ int cur[256];
    __shared__ int win[CAP];
    int b = blockIdx.x, tid = threadIdx.x;
    int node0 = b * 256;
    deg[tid] = 0; cur[tid] = 0;
    __syncthreads();
    int m = bcnt[b]; if (m > CAP) m = CAP;
    const int2* eb = ebuf + (size_t)b * CAP;
    for (int i = tid; i < m; i += 256)
        atomicAdd(&deg[eb[i].y & 255], 1);
    __syncthreads();
    int v = deg[tid];
    loc[tid] = v;
    __syncthreads();
    for (int off = 1; off < 256; off <<= 1) {
        int u = (tid >= off) ? loc[tid - off] : 0;
        __syncthreads();
        loc[tid] += u;
        __syncthreads();
    }
    int excl = loc[tid] - v;
    int node = node0 + tid;
    if (node < n) {
        row_ptr[node] = boff[b] + excl;
        dis[node] = rsqrtf((float)v + 1.0f);
        if (v > 32) {
            int ix = atomicAdd(ovf_cnt, 1);
            if (ix < OVF_CAP) ovf[ix] = node;
        }
    }
    loc[tid] = excl;
    __syncthreads();
    for (int i = tid; i < m; i += 256) {
        int2 ed = eb[i];
        int ll = ed.y & 255;
        int pos = loc[ll] + atomicAdd(&cur[ll], 1);
        win[pos] = ed.x << 8;                       // pre-shifted byte offset
    }
    __syncthreads();
    int base0 = boff[b];
    for (int i = tid; i < m; i += 256) col[base0 + i] = win[i];
    // padded fixed-stride dump (coalesced)
    for (int slot = tid; slot < 256 * 32; slot += 256) {
        int nl = slot >> 5, s = slot & 31;
        if (node0 + nl < n) {
            int d = deg[nl];
            col32[(size_t)node0 * 32 + slot] = (s < d) ? win[loc[nl] + s] : PAD_V;
        }
    }
}

// ---------------- canonicalize: fixed 32-element bitonic per node window ----------------
// 2 nodes per wave (32-lane halves). PAD_V is the max value -> pads sort to the end.
// Extra tail block: serial insertion-sort of packed CSR rows for overflow nodes.
__global__ __launch_bounds__(256) void rowsort32_k(int* __restrict__ col32,
                                                   const int* __restrict__ rp,
                                                   int* __restrict__ col,
                                                   const int* __restrict__ ovf,
                                                   const int* __restrict__ ovf_cnt,
                                                   int n, int nblk) {
    if ((int)blockIdx.x < nblk) {
        int lane = threadIdx.x & 63;
        int sub  = lane >> 5;                 // 0/1: which node in the wave
        int l32  = lane & 31;
        int node = blockIdx.x * 8 + (threadIdx.x >> 6) * 2 + sub;
        if (node >= n) return;
        int* wp = col32 + (size_t)node * 32;
        int v = wp[l32];
#pragma unroll
        for (int k = 2; k <= 32; k <<= 1)
#pragma unroll
            for (int j = k >> 1; j > 0; j >>= 1) {
                int other = __shfl_xor(v, j);
                bool up    = (l32 & k) == 0;
                bool small = (l32 & j) == 0;
                v = (small == up) ? min(v, other) : max(v, other);
            }
        wp[l32] = v;
    } else {
        int cnt = *ovf_cnt; if (cnt > OVF_CAP) cnt = OVF_CAP;
        for (int i = threadIdx.x; i < cnt; i += 256) {
            int node = ovf[i];
            int beg = rp[node], end = rp[node + 1];
            for (int a = beg + 1; a < end; ++a) {
                int key = col[a]; int j = a - 1;
                while (j >= beg && col[j] > key) { col[j + 1] = col[j]; --j; }
                col[j + 1] = key;
            }
        }
    }
}

// ---- fp32 -> bf16 (RTNE) ----
__device__ inline ushort f2bf(float f) {
    unsigned u = __float_as_uint(f);
    unsigned rounding = 0x7fffu + ((u >> 16) & 1u);
    return (ushort)((u + rounding) >> 16);
}
__device__ inline float bf_lo(uint v) { return __uint_as_float(v << 16); }
__device__ inline float bf_hi(uint v) { return __uint_as_float(v & 0xffff0000u); }
__device__ inline short8 cvt8(float4 f0, float4 f1) {
    short8 r;
    r[0] = (short)f2bf(f0.x); r[1] = (short)f2bf(f0.y);
    r[2] = (short)f2bf(f0.z); r[3] = (short)f2bf(f0.w);
    r[4] = (short)f2bf(f1.x); r[5] = (short)f2bf(f1.y);
    r[6] = (short)f2bf(f1.z); r[7] = (short)f2bf(f1.w);
    return r;
}

// async global -> LDS (16B per lane; LDS dest = wave-uniform base + lane*16)
__device__ inline void gload16(const void* g, void* l) {
    __builtin_amdgcn_global_load_lds(
        (const __attribute__((address_space(1))) uint*)g,
        (__attribute__((address_space(3))) uint*)l, 16, 0, 0);
}

// ---------------- all three W -> Wt bf16, one launch; also zero hb pad row N ----------------
__global__ void wtrans_all_k(const float* __restrict__ W0, const float* __restrict__ W1,
                             const float* __restrict__ W2, ushort* __restrict__ Wt0,
                             ushort* __restrict__ Wt1, ushort* __restrict__ Wt2,
                             uint* __restrict__ hb_padrow) {
    int i = blockIdx.x * 256 + threadIdx.x;   // 0..65535
    if (i < 64) hb_padrow[i] = 0;             // zero row N of hb (gather target for pads)
    const float* W; ushort* Wt; int K, j;
    if (i < 32768)      { W = W0; Wt = Wt0; K = 256; j = i; }
    else if (i < 49152) { W = W1; Wt = Wt1; K = 128; j = i - 32768; }
    else                { W = W2; Wt = Wt2; K = 128; j = i - 49152; }
    int k = j >> 7, n = j & 127;
    Wt[(size_t)n * K + k] = f2bf(W[j]);
}

// ---------------- MFMA GEMM: global_load_lds staged A tile, register-resident B ----------------
template<int K, int ROWS, bool AF32>
__global__ __launch_bounds__(256) void gemm_lds_k(const void* __restrict__ Ap,
                                                  const ushort* __restrict__ Bt, // [128][K]
                                                  const float* __restrict__ dis,
                                                  ushort* __restrict__ H,        // [(M+1)][128]
                                                  int M) {
    constexpr int T  = K / 32;                 // MFMA k-steps
    constexpr int EB = AF32 ? 4 : 2;           // element bytes
    constexpr int RS = K * EB;                 // row stride bytes
    constexpr int NI = (ROWS * RS) / 4096;     // staging iters (4 waves x 1KB)
    __shared__ char As[ROWS * RS];

    int tid = threadIdx.x;
    int w = tid >> 6, l = tid & 63, lr = l & 15, hi = l >> 4;
    int cBase = w * 32;

    short8 b[2][T];
#pragma unroll
    for (int c = 0; c < 2; ++c)
#pragma unroll
        for (int t = 0; t < T; ++t)
            b[c][t] = *(const short8*)&Bt[(size_t)(cBase + c * 16 + lr) * K + t * 32 + hi * 8];

    int r0 = blockIdx.x * ROWS;
    const char* gbase = (const char*)Ap + (size_t)r0 * RS;

#pragma unroll
    for (int i = 0; i < NI; ++i) {
        int L0  = (i * 4 + w) * 1024;          // wave-uniform LDS base
        int L   = L0 + l * 16;
        int row = L / RS;
        int cb  = (L % RS) >> 4;
        int gb  = (cb ^ (row & 7)) << 4;
        int grow = (r0 + row < M) ? row : 0;   // tail clamp (masked at store)
        gload16(gbase + (size_t)grow * RS + gb, &As[L0]);
    }
    __syncthreads();

    f32x4 acc[ROWS / 16][2];
#pragma unroll
    for (int rb = 0; rb < ROWS / 16; ++rb)
#pragma unroll
        for (int c = 0; c < 2; ++c) acc[rb][c] = (f32x4){0.f, 0.f, 0.f, 0.f};

#pragma unroll
    for (int rb = 0; rb < ROWS / 16; ++rb) {
        int row = rb * 16 + lr;
        int s = row & 7;
        const char* rbase = &As[row * RS];
#pragma unroll
        for (int t = 0; t < T; ++t) {
            short8 a;
            if constexpr (AF32) {
                int cb0 = t * 8 + hi * 2;
                float4 f0 = *(const float4*)(rbase + ((cb0 ^ s) << 4));
                float4 f1 = *(const float4*)(rbase + (((cb0 + 1) ^ s) << 4));
                a = cvt8(f0, f1);
            } else {
                int cb0 = t * 4 + hi;
                a = *(const short8*)(rbase + ((cb0 ^ s) << 4));
            }
#pragma unroll
            for (int c = 0; c < 2; ++c)
                acc[rb][c] = __builtin_amdgcn_mfma_f32_16x16x32_bf16(a, b[c][t], acc[rb][c], 0, 0, 0);
        }
    }

#pragma unroll
    for (int rb = 0; rb < ROWS / 16; ++rb) {
#pragma unroll
        for (int j = 0; j < 4; ++j) {
            int r = r0 + rb * 16 + hi * 4 + j;
            if (r < M) {
                float d = dis[r];
#pragma unroll
                for (int c = 0; c < 2; ++c)
                    H[(size_t)r * 128 + cBase + c * 16 + lr] = f2bf(acc[rb][c][j] * d);
            }
        }
    }
}

// ---------------- main aggregate: straight-line, fixed 32 slots, column-half split ----------------
// wave = one node-half: 8 slot-groups (g) x 8 col-blocks (cl); 4 slots per group.
// out = relu(dis[n]*(sum hs[slots] + hs[n]) + b); pads gather the zero row.
template<bool LAST>
__global__ __launch_bounds__(256) void aggregate_k(const ushort* __restrict__ hs,
                                                   const int* __restrict__ col32,
                                                   const float* __restrict__ dis,
                                                   const float* __restrict__ bias,
                                                   ushort* __restrict__ act,
                                                   float* __restrict__ out, int halfG) {
    int bid  = blockIdx.x;
    int half = (bid >= halfG) ? 1 : 0;
    int node = (bid - half * halfG) * 4 + (threadIdx.x >> 6);
    int lane = threadIdx.x & 63;
    int g  = lane >> 3;          // slot group 0..7
    int cl = lane & 7;           // 16B col block within the half
    const char* base = (const char*)hs + half * 128 + (cl << 4);

    const int* cw = col32 + (size_t)node * 32 + g * 4;
    int s0 = cw[0], s1 = cw[1], s2 = cw[2], s3 = cw[3];
    uint4 u0 = *(const uint4*)(base + (size_t)(uint)s0);
    uint4 u1 = *(const uint4*)(base + (size_t)(uint)s1);
    uint4 u2 = *(const uint4*)(base + (size_t)(uint)s2);
    uint4 u3 = *(const uint4*)(base + (size_t)(uint)s3);

    float2 ax[4];
#pragma unroll
    for (int i = 0; i < 4; ++i) ax[i] = make_float2(0.f, 0.f);
    uint4 uu[4] = {u0, u1, u2, u3};
#pragma unroll
    for (int q = 0; q < 4; ++q) {
        ax[0].x += bf_lo(uu[q].x); ax[0].y += bf_hi(uu[q].x);
        ax[1].x += bf_lo(uu[q].y); ax[1].y += bf_hi(uu[q].y);
        ax[2].x += bf_lo(uu[q].z); ax[2].y += bf_hi(uu[q].z);
        ax[3].x += bf_lo(uu[q].w); ax[3].y += bf_hi(uu[q].w);
    }
    float o[8] = {ax[0].x, ax[0].y, ax[1].x, ax[1].y, ax[2].x, ax[2].y, ax[3].x, ax[3].y};
#pragma unroll
    for (int j = 0; j < 8; ++j) {
        o[j] += __shfl_xor(o[j], 8);
        o[j] += __shfl_xor(o[j], 16);
        o[j] += __shfl_xor(o[j], 32);
    }
    if (g == 0) {
        float dn = dis[node];
        uint4 un = *(const uint4*)(base + ((size_t)node << 8));
        float hsn[8] = {bf_lo(un.x), bf_hi(un.x), bf_lo(un.y), bf_hi(un.y),
                        bf_lo(un.z), bf_hi(un.z), bf_lo(un.w), bf_hi(un.w)};
        int c0 = half * 64 + cl * 8;
        float4 bv0 = *(const float4*)&bias[c0];
        float4 bv1 = *(const float4*)&bias[c0 + 4];
        float bb[8] = {bv0.x, bv0.y, bv0.z, bv0.w, bv1.x, bv1.y, bv1.z, bv1.w};
#pragma unroll
        for (int j = 0; j < 8; ++j)
            o[j] = fmaxf((o[j] + hsn[j]) * dn + bb[j], 0.f);
        if (LAST) {
            *(float4*)&out[(size_t)node * D_HID + c0]     = make_float4(o[0], o[1], o[2], o[3]);
            *(float4*)&out[(size_t)node * D_HID + c0 + 4] = make_float4(o[4], o[5], o[6], o[7]);
        } else {
            uint4 p;
            p.x = (uint)f2bf(o[0]) | ((uint)f2bf(o[1]) << 16);
            p.y = (uint)f2bf(o[2]) | ((uint)f2bf(o[3]) << 16);
            p.z = (uint)f2bf(o[4]) | ((uint)f2bf(o[5]) << 16);
            p.w = (uint)f2bf(o[6]) | ((uint)f2bf(o[7]) << 16);
            *(uint4*)((char*)act + ((size_t)node << 8) + half * 128 + (cl << 4)) = p;
        }
    }
}

// ---------------- overflow aggregate: full CSR recompute for deg>32 nodes ----------------
template<bool LAST>
__global__ __launch_bounds__(256) void ovf_agg_k(const ushort* __restrict__ hs,
                                                 const int* __restrict__ rp,
                                                 const int* __restrict__ col,
                                                 const float* __restrict__ dis,
                                                 const float* __restrict__ bias,
                                                 ushort* __restrict__ act,
                                                 float* __restrict__ out,
                                                 const int* __restrict__ ovf,
                                                 const int* __restrict__ ovf_cnt) {
    int cnt = *ovf_cnt; if (cnt > OVF_CAP) cnt = OVF_CAP;
    int wid = threadIdx.x >> 6, lane = threadIdx.x & 63;
    int g = lane >> 4, cl = lane & 15;
    const char* base = (const char*)hs + (cl << 4);
    for (int i = wid; i < cnt; i += 4) {
        int node = ovf[i];
        float ax[8];
#pragma unroll
        for (int j = 0; j < 8; ++j) ax[j] = 0.f;
        int beg = rp[node], end = rp[node + 1];
        for (int e = beg; e < end; e += 4) {
            int idx = e + g;
            int s = (idx < end) ? col[idx] : PAD_V;
            uint4 u = *(const uint4*)(base + (size_t)(uint)s);
            ax[0] += bf_lo(u.x); ax[1] += bf_hi(u.x);
            ax[2] += bf_lo(u.y); ax[3] += bf_hi(u.y);
            ax[4] += bf_lo(u.z); ax[5] += bf_hi(u.z);
            ax[6] += bf_lo(u.w); ax[7] += bf_hi(u.w);
        }
#pragma unroll
        for (int j = 0; j < 8; ++j) {
            ax[j] += __shfl_xor(ax[j], 16);
            ax[j] += __shfl_xor(ax[j], 32);
        }
        if (g == 0) {
            float dn = dis[node];
            uint4 un = *(const uint4*)(base + ((size_t)node << 8));
            float hsn[8] = {bf_lo(un.x), bf_hi(un.x), bf_lo(un.y), bf_hi(un.y),
                            bf_lo(un.z), bf_hi(un.z), bf_lo(un.w), bf_hi(un.w)};
            int c0 = cl * 8;
            float4 bv0 = *(const float4*)&bias[c0];
            float4 bv1 = *(const float4*)&bias[c0 + 4];
            float bb[8] = {bv0.x, bv0.y, bv0.z, bv0.w, bv1.x, bv1.y, bv1.z, bv1.w};
            float o[8];
#pragma unroll
            for (int j = 0; j < 8; ++j)
                o[j] = fmaxf((ax[j] + hsn[j]) * dn + bb[j], 0.f);
            if (LAST) {
                *(float4*)&out[(size_t)node * D_HID + c0]     = make_float4(o[0], o[1], o[2], o[3]);
                *(float4*)&out[(size_t)node * D_HID + c0 + 4] = make_float4(o[4], o[5], o[6], o[7]);
            } else {
                uint4 p;
                p.x = (uint)f2bf(o[0]) | ((uint)f2bf(o[1]) << 16);
                p.y = (uint)f2bf(o[2]) | ((uint)f2bf(o[3]) << 16);
                p.z = (uint)f2bf(o[4]) | ((uint)f2bf(o[5]) << 16);
                p.w = (uint)f2bf(o[6]) | ((uint)f2bf(o[7]) << 16);
                *(uint4*)((char*)act + ((size_t)node << 8) + (cl << 4)) = p;
            }
        }
    }
}

extern "C" void kernel_launch(void* const* d_in, const int* in_sizes, int n_in,
                              void* d_out, int out_size, void* d_ws, size_t ws_size,
                              hipStream_t stream) {
    const float* x  = (const float*)d_in[0];
    const int*   ei = (const int*)d_in[1];
    const float* W0 = (const float*)d_in[2];
    const float* b0 = (const float*)d_in[3];
    const float* W1 = (const float*)d_in[4];
    const float* b1 = (const float*)d_in[5];
    const float* W2 = (const float*)d_in[6];
    const float* b2 = (const float*)d_in[7];
    float* out = (float*)d_out;

    const int N = N_NODES, E = N_EDGES;
    const int* src = ei;
    const int* dst = ei + E;

    char* w = (char*)d_ws;
    size_t off = 0;
    auto alloc = [&](size_t bytes) {
        size_t o = off;
        off += (bytes + 255) & ~(size_t)255;
        return o;
    };
    int*    bcur   = (int*)(w + alloc((size_t)(NB + 1) * 4));   // [NB]=ovf_cnt
    int*    ovf    = (int*)(w + alloc((size_t)OVF_CAP * 4));
    float*  dis    = (float*)(w + alloc((size_t)N * 4));
    int*    rp     = (int*)(w + alloc((size_t)(N + 1) * 4));
    int*    boff   = (int*)(w + alloc((size_t)NB * 4));
    int*    col    = (int*)(w + alloc((size_t)E * 4));
    int*    col32  = (int*)(w + alloc((size_t)N * 32 * 4));
    int2*   ebuf   = (int2*)(w + alloc((size_t)NB * CAP * 8));
    ushort* hb     = (ushort*)(w + alloc((size_t)(N + 1) * D_HID * 2));  // +1 zero pad row
    ushort* act    = (ushort*)(w + alloc((size_t)N * D_HID * 2));
    ushort* Wt0    = (ushort*)(w + alloc((size_t)128 * 256 * 2));
    ushort* Wt1    = (ushort*)(w + alloc((size_t)128 * 128 * 2));
    ushort* Wt2    = (ushort*)(w + alloc((size_t)128 * 128 * 2));
    int*    ovf_cnt = bcur + NB;
    (void)ws_size; (void)n_in; (void)in_sizes; (void)out_size;

    hipMemsetAsync(bcur, 0, (size_t)(NB + 1) * 4, stream);

    part_k<<<P1_BLOCKS, 256, 0, stream>>>(src, dst, bcur, ebuf, E);
    bscan196_k<<<1, 256, 0, stream>>>(bcur, boff, rp + N);
    csr2_k<<<NB, 256, 0, stream>>>(ebuf, bcur, boff, rp, dis, col, col32, ovf, ovf_cnt, N);
    int srt_blocks = (N + 7) / 8;   // 6250
    rowsort32_k<<<srt_blocks + 1, 256, 0, stream>>>(col32, rp, col, ovf, ovf_cnt, N, srt_blocks);

    wtrans_all_k<<<256, 256, 0, stream>>>(W0, W1, W2, Wt0, Wt1, Wt2,
                                          (uint*)(hb + (size_t)N * D_HID));

    int g32 = (N + 31) / 32;    // 1563 (layer 0, 32-row tiles)
    int g64 = (N + 63) / 64;    // 782  (layers 1-2, 64-row tiles)
    int halfG = N / 4;          // 12500 blocks per column half
    int agg_grid = 2 * halfG;

    // layer 0
    gemm_lds_k<256, 32, true><<<g32, 256, 0, stream>>>(x, Wt0, dis, hb, N);
    aggregate_k<false><<<agg_grid, 256, 0, stream>>>(hb, col32, dis, b0, act, out, halfG);
    ovf_agg_k<false><<<1, 256, 0, stream>>>(hb, rp, col, dis, b0, act, out, ovf, ovf_cnt);
    // layer 1
    gemm_lds_k<128, 64, false><<<g64, 256, 0, stream>>>(act, Wt1, dis, hb, N);
    aggregate_k<false><<<agg_grid, 256, 0, stream>>>(hb, col32, dis, b1, act, out, halfG);
    ovf_agg_k<false><<<1, 256, 0, stream>>>(hb, rp, col, dis, b1, act, out, ovf, ovf_cnt);
    // layer 2
    gemm_lds_k<128, 64, false><<<g64, 256, 0, stream>>>(act, Wt2, dis, hb, N);
    aggregate_k<true><<<agg_grid, 256, 0, stream>>>(hb, col32, dis, b2, act, out, halfG);
    ovf_agg_k<true><<<1, 256, 0, stream>>>(hb, rp, col, dis, b2, act, out, ovf, ovf_cnt);
}

// Round 16
// 256.701 us; speedup vs baseline: 1.2923x; 1.2923x over previous
//
#include <hip/hip_runtime.h>

#define N_NODES 50000
#define N_EDGES 800000
#define D_HID   128
#define PAD_V   (N_NODES << 8)             // pad slot: byte offset of zero row N

typedef unsigned int uint;
typedef unsigned short ushort;
typedef __attribute__((ext_vector_type(8))) short short8;
typedef __attribute__((ext_vector_type(4))) float f32x4;

#define NB       196                       // dst buckets of 256 nodes
#define CAP      6144                      // per-bucket ebuf capacity
#define P1_BLOCKS 200
#define P1_CHUNK  4000                     // 200 * 4000 = 800000 exactly
#define OVF_CAP  1024

// ---------------- P1: partition edges into dst-range buckets ----------------
__global__ __launch_bounds__(256) void part_k(const int* __restrict__ src,
                                              const int* __restrict__ dst,
                                              int* __restrict__ bcur,
                                              int2* __restrict__ ebuf, int e) {
    __shared__ int hist[NB];
    __shared__ int base[NB];
    int tid = threadIdx.x;
    if (tid < NB) hist[tid] = 0;
    __syncthreads();

    int e0 = blockIdx.x * P1_CHUNK;
    int2 ed[16];
    bool val[16];
#pragma unroll
    for (int i = 0; i < 16; ++i) {
        int o = i * 256 + tid;
        int idx = e0 + o;
        val[i] = (o < P1_CHUNK) && (idx < e);
        if (val[i]) {
            ed[i] = make_int2(src[idx], dst[idx]);
            atomicAdd(&hist[ed[i].y >> 8], 1);
        }
    }
    __syncthreads();
    if (tid < NB && hist[tid] > 0) base[tid] = atomicAdd(&bcur[tid], hist[tid]);
    __syncthreads();
    if (tid < NB) hist[tid] = 0;
    __syncthreads();
#pragma unroll
    for (int i = 0; i < 16; ++i) {
        if (val[i]) {
            int bk = ed[i].y >> 8;
            int o  = base[bk] + atomicAdd(&hist[bk], 1);
            if (o < CAP) ebuf[(size_t)bk * CAP + o] = ed[i];
        }
    }
}

// ---------------- scan of per-bucket totals (bcur) -> boff, row_ptr[N] ----------------
__global__ void bscan196_k(const int* __restrict__ bcur, int* __restrict__ boff,
                           int* __restrict__ row_ptr_end) {
    __shared__ int s[256];
    int t = threadIdx.x;
    int v = (t < NB) ? bcur[t] : 0;
    s[t] = v;
    __syncthreads();
    for (int off = 1; off < 256; off <<= 1) {
        int u = (t >= off) ? s[t - off] : 0;
        __syncthreads();
        s[t] += u;
        __syncthreads();
    }
    if (t < NB) boff[t] = s[t] - v;        // exclusive
    if (t == 255) *row_ptr_end = s[255];   // total -> row_ptr[n]
}

// ---------------- merged CSR build: count+scan+scatter+packed dump+padded dump ----------------
// col  : packed CSR (src<<8), for overflow nodes
// col32: fixed-stride 32 windows (src<<8, PAD_V sentinel pads), for the main aggregate
__global__ __launch_bounds__(256) void csr2_k(const int2* __restrict__ ebuf,
                                              const int* __restrict__ bcnt,
                                              const int* __restrict__ boff,
                                              int* __restrict__ row_ptr,
                                              float* __restrict__ dis,
                                              int* __restrict__ col,
                                              int* __restrict__ col32,
                                              int* __restrict__ ovf,
                                              int* __restrict__ ovf_cnt, int n) {
    __shared__ int deg[256];
    __shared__ int loc[256];
    __shared__ int cur[256];
    __shared__ int win[CAP];
    int b = blockIdx.x, tid = threadIdx.x;
    int node0 = b * 256;
    deg[tid] = 0; cur[tid] = 0;
    __syncthreads();
    int m = bcnt[b]; if (m > CAP) m = CAP;
    const int2* eb = ebuf + (size_t)b * CAP;
    for (int i = tid; i < m; i += 256)
        atomicAdd(&deg[eb[i].y & 255], 1);
    __syncthreads();
    int v = deg[tid];
    loc[tid] = v;
    __syncthreads();
    for (int off = 1; off < 256; off <<= 1) {
        int u = (tid >= off) ? loc[tid - off] : 0;
        __syncthreads();
        loc[tid] += u;
        __syncthreads();
    }
    int excl = loc[tid] - v;
    int node = node0 + tid;
    if (node < n) {
        row_ptr[node] = boff[b] + excl;
        dis[node] = rsqrtf((float)v + 1.0f);
        if (v > 32) {
            int ix = atomicAdd(ovf_cnt, 1);
            if (ix < OVF_CAP) ovf[ix] = node;
        }
    }
    loc[tid] = excl;
    __syncthreads();
    for (int i = tid; i < m; i += 256) {
        int2 ed = eb[i];
        int ll = ed.y & 255;
        int pos = loc[ll] + atomicAdd(&cur[ll], 1);
        win[pos] = ed.x << 8;                       // pre-shifted byte offset
    }
    __syncthreads();
    int base0 = boff[b];
    for (int i = tid; i < m; i += 256) col[base0 + i] = win[i];
    // padded fixed-stride dump (coalesced)
    for (int slot = tid; slot < 256 * 32; slot += 256) {
        int nl = slot >> 5, s = slot & 31;
        if (node0 + nl < n) {
            int d = deg[nl];
            col32[(size_t)node0 * 32 + slot] = (s < d) ? win[loc[nl] + s] : PAD_V;
        }
    }
}

// ---------------- canonicalize: fixed 32-element bitonic per node window ----------------
// Main blocks: 2 nodes per wave (32-lane halves), PAD_V sorts to the end.
// Tail block: WAVE-PARALLEL 64-lane bitonic per overflow node's packed CSR row
// (serial fallback only for deg>64, which this dataset never hits).
__global__ __launch_bounds__(256) void rowsort32_k(int* __restrict__ col32,
                                                   const int* __restrict__ rp,
                                                   int* __restrict__ col,
                                                   const int* __restrict__ ovf,
                                                   const int* __restrict__ ovf_cnt,
                                                   int n, int nblk) {
    if ((int)blockIdx.x < nblk) {
        int lane = threadIdx.x & 63;
        int sub  = lane >> 5;                 // 0/1: which node in the wave
        int l32  = lane & 31;
        int node = blockIdx.x * 8 + (threadIdx.x >> 6) * 2 + sub;
        if (node >= n) return;
        int* wp = col32 + (size_t)node * 32;
        int v = wp[l32];
#pragma unroll
        for (int k = 2; k <= 32; k <<= 1)
#pragma unroll
            for (int j = k >> 1; j > 0; j >>= 1) {
                int other = __shfl_xor(v, j);
                bool up    = (l32 & k) == 0;
                bool small = (l32 & j) == 0;
                v = (small == up) ? min(v, other) : max(v, other);
            }
        wp[l32] = v;
    } else {
        int cnt = *ovf_cnt; if (cnt > OVF_CAP) cnt = OVF_CAP;
        int wid = threadIdx.x >> 6, lane = threadIdx.x & 63;
        for (int i = wid; i < cnt; i += 4) {
            int node = ovf[i];
            int beg = rp[node], end = rp[node + 1];
            int len = end - beg;
            if (len <= 64) {
                int v = (lane < len) ? col[beg + lane] : 0x7fffffff;
#pragma unroll
                for (int k = 2; k <= 64; k <<= 1)
#pragma unroll
                    for (int j = k >> 1; j > 0; j >>= 1) {
                        int other = __shfl_xor(v, j);
                        bool up    = (lane & k) == 0;
                        bool small = (lane & j) == 0;
                        v = (small == up) ? min(v, other) : max(v, other);
                    }
                if (lane < len) col[beg + lane] = v;
            } else if (lane == 0) {     // unreachable for this dataset
                for (int a = beg + 1; a < end; ++a) {
                    int key = col[a]; int j = a - 1;
                    while (j >= beg && col[j] > key) { col[j + 1] = col[j]; --j; }
                    col[j + 1] = key;
                }
            }
        }
    }
}

// ---- fp32 -> bf16 (RTNE) ----
__device__ inline ushort f2bf(float f) {
    unsigned u = __float_as_uint(f);
    unsigned rounding = 0x7fffu + ((u >> 16) & 1u);
    return (ushort)((u + rounding) >> 16);
}
__device__ inline float bf_lo(uint v) { return __uint_as_float(v << 16); }
__device__ inline float bf_hi(uint v) { return __uint_as_float(v & 0xffff0000u); }
__device__ inline short8 cvt8(float4 f0, float4 f1) {
    short8 r;
    r[0] = (short)f2bf(f0.x); r[1] = (short)f2bf(f0.y);
    r[2] = (short)f2bf(f0.z); r[3] = (short)f2bf(f0.w);
    r[4] = (short)f2bf(f1.x); r[5] = (short)f2bf(f1.y);
    r[6] = (short)f2bf(f1.z); r[7] = (short)f2bf(f1.w);
    return r;
}

// async global -> LDS (16B per lane; LDS dest = wave-uniform base + lane*16)
__device__ inline void gload16(const void* g, void* l) {
    __builtin_amdgcn_global_load_lds(
        (const __attribute__((address_space(1))) uint*)g,
        (__attribute__((address_space(3))) uint*)l, 16, 0, 0);
}

// ---------------- all three W -> Wt bf16, one launch; also zero hb pad row N ----------------
__global__ void wtrans_all_k(const float* __restrict__ W0, const float* __restrict__ W1,
                             const float* __restrict__ W2, ushort* __restrict__ Wt0,
                             ushort* __restrict__ Wt1, ushort* __restrict__ Wt2,
                             uint* __restrict__ hb_padrow) {
    int i = blockIdx.x * 256 + threadIdx.x;   // 0..65535
    if (i < 64) hb_padrow[i] = 0;             // zero row N of hb (gather target for pads)
    const float* W; ushort* Wt; int K, j;
    if (i < 32768)      { W = W0; Wt = Wt0; K = 256; j = i; }
    else if (i < 49152) { W = W1; Wt = Wt1; K = 128; j = i - 32768; }
    else                { W = W2; Wt = Wt2; K = 128; j = i - 49152; }
    int k = j >> 7, n = j & 127;
    Wt[(size_t)n * K + k] = f2bf(W[j]);
}

// ---------------- MFMA GEMM: global_load_lds staged A tile, register-resident B ----------------
template<int K, int ROWS, bool AF32>
__global__ __launch_bounds__(256) void gemm_lds_k(const void* __restrict__ Ap,
                                                  const ushort* __restrict__ Bt, // [128][K]
                                                  const float* __restrict__ dis,
                                                  ushort* __restrict__ H,        // [(M+1)][128]
                                                  int M) {
    constexpr int T  = K / 32;                 // MFMA k-steps
    constexpr int EB = AF32 ? 4 : 2;           // element bytes
    constexpr int RS = K * EB;                 // row stride bytes
    constexpr int NI = (ROWS * RS) / 4096;     // staging iters (4 waves x 1KB)
    __shared__ char As[ROWS * RS];

    int tid = threadIdx.x;
    int w = tid >> 6, l = tid & 63, lr = l & 15, hi = l >> 4;
    int cBase = w * 32;

    short8 b[2][T];
#pragma unroll
    for (int c = 0; c < 2; ++c)
#pragma unroll
        for (int t = 0; t < T; ++t)
            b[c][t] = *(const short8*)&Bt[(size_t)(cBase + c * 16 + lr) * K + t * 32 + hi * 8];

    int r0 = blockIdx.x * ROWS;
    const char* gbase = (const char*)Ap + (size_t)r0 * RS;

#pragma unroll
    for (int i = 0; i < NI; ++i) {
        int L0  = (i * 4 + w) * 1024;          // wave-uniform LDS base
        int L   = L0 + l * 16;
        int row = L / RS;
        int cb  = (L % RS) >> 4;
        int gb  = (cb ^ (row & 7)) << 4;
        int grow = (r0 + row < M) ? row : 0;   // tail clamp (masked at store)
        gload16(gbase + (size_t)grow * RS + gb, &As[L0]);
    }
    __syncthreads();

    f32x4 acc[ROWS / 16][2];
#pragma unroll
    for (int rb = 0; rb < ROWS / 16; ++rb)
#pragma unroll
        for (int c = 0; c < 2; ++c) acc[rb][c] = (f32x4){0.f, 0.f, 0.f, 0.f};

#pragma unroll
    for (int rb = 0; rb < ROWS / 16; ++rb) {
        int row = rb * 16 + lr;
        int s = row & 7;
        const char* rbase = &As[row * RS];
#pragma unroll
        for (int t = 0; t < T; ++t) {
            short8 a;
            if constexpr (AF32) {
                int cb0 = t * 8 + hi * 2;
                float4 f0 = *(const float4*)(rbase + ((cb0 ^ s) << 4));
                float4 f1 = *(const float4*)(rbase + (((cb0 + 1) ^ s) << 4));
                a = cvt8(f0, f1);
            } else {
                int cb0 = t * 4 + hi;
                a = *(const short8*)(rbase + ((cb0 ^ s) << 4));
            }
#pragma unroll
            for (int c = 0; c < 2; ++c)
                acc[rb][c] = __builtin_amdgcn_mfma_f32_16x16x32_bf16(a, b[c][t], acc[rb][c], 0, 0, 0);
        }
    }

#pragma unroll
    for (int rb = 0; rb < ROWS / 16; ++rb) {
#pragma unroll
        for (int j = 0; j < 4; ++j) {
            int r = r0 + rb * 16 + hi * 4 + j;
            if (r < M) {
                float d = dis[r];
#pragma unroll
                for (int c = 0; c < 2; ++c)
                    H[(size_t)r * 128 + cBase + c * 16 + lr] = f2bf(acc[rb][c][j] * d);
            }
        }
    }
}

// ---------------- main aggregate: straight-line, fixed 32 slots, column-half split ----------------
template<bool LAST>
__global__ __launch_bounds__(256) void aggregate_k(const ushort* __restrict__ hs,
                                                   const int* __restrict__ col32,
                                                   const float* __restrict__ dis,
                                                   const float* __restrict__ bias,
                                                   ushort* __restrict__ act,
                                                   float* __restrict__ out, int halfG) {
    int bid  = blockIdx.x;
    int half = (bid >= halfG) ? 1 : 0;
    int node = (bid - half * halfG) * 4 + (threadIdx.x >> 6);
    int lane = threadIdx.x & 63;
    int g  = lane >> 3;          // slot group 0..7
    int cl = lane & 7;           // 16B col block within the half
    const char* base = (const char*)hs + half * 128 + (cl << 4);

    const int* cw = col32 + (size_t)node * 32 + g * 4;
    int s0 = cw[0], s1 = cw[1], s2 = cw[2], s3 = cw[3];
    uint4 u0 = *(const uint4*)(base + (size_t)(uint)s0);
    uint4 u1 = *(const uint4*)(base + (size_t)(uint)s1);
    uint4 u2 = *(const uint4*)(base + (size_t)(uint)s2);
    uint4 u3 = *(const uint4*)(base + (size_t)(uint)s3);

    float2 ax[4];
#pragma unroll
    for (int i = 0; i < 4; ++i) ax[i] = make_float2(0.f, 0.f);
    uint4 uu[4] = {u0, u1, u2, u3};
#pragma unroll
    for (int q = 0; q < 4; ++q) {
        ax[0].x += bf_lo(uu[q].x); ax[0].y += bf_hi(uu[q].x);
        ax[1].x += bf_lo(uu[q].y); ax[1].y += bf_hi(uu[q].y);
        ax[2].x += bf_lo(uu[q].z); ax[2].y += bf_hi(uu[q].z);
        ax[3].x += bf_lo(uu[q].w); ax[3].y += bf_hi(uu[q].w);
    }
    float o[8] = {ax[0].x, ax[0].y, ax[1].x, ax[1].y, ax[2].x, ax[2].y, ax[3].x, ax[3].y};
#pragma unroll
    for (int j = 0; j < 8; ++j) {
        o[j] += __shfl_xor(o[j], 8);
        o[j] += __shfl_xor(o[j], 16);
        o[j] += __shfl_xor(o[j], 32);
    }
    if (g == 0) {
        float dn = dis[node];
        uint4 un = *(const uint4*)(base + ((size_t)node << 8));
        float hsn[8] = {bf_lo(un.x), bf_hi(un.x), bf_lo(un.y), bf_hi(un.y),
                        bf_lo(un.z), bf_hi(un.z), bf_lo(un.w), bf_hi(un.w)};
        int c0 = half * 64 + cl * 8;
        float4 bv0 = *(const float4*)&bias[c0];
        float4 bv1 = *(const float4*)&bias[c0 + 4];
        float bb[8] = {bv0.x, bv0.y, bv0.z, bv0.w, bv1.x, bv1.y, bv1.z, bv1.w};
#pragma unroll
        for (int j = 0; j < 8; ++j)
            o[j] = fmaxf((o[j] + hsn[j]) * dn + bb[j], 0.f);
        if (LAST) {
            *(float4*)&out[(size_t)node * D_HID + c0]     = make_float4(o[0], o[1], o[2], o[3]);
            *(float4*)&out[(size_t)node * D_HID + c0 + 4] = make_float4(o[4], o[5], o[6], o[7]);
        } else {
            uint4 p;
            p.x = (uint)f2bf(o[0]) | ((uint)f2bf(o[1]) << 16);
            p.y = (uint)f2bf(o[2]) | ((uint)f2bf(o[3]) << 16);
            p.z = (uint)f2bf(o[4]) | ((uint)f2bf(o[5]) << 16);
            p.w = (uint)f2bf(o[6]) | ((uint)f2bf(o[7]) << 16);
            *(uint4*)((char*)act + ((size_t)node << 8) + half * 128 + (cl << 4)) = p;
        }
    }
}

// ---------------- overflow aggregate: full CSR recompute for deg>32 nodes ----------------
template<bool LAST>
__global__ __launch_bounds__(256) void ovf_agg_k(const ushort* __restrict__ hs,
                                                 const int* __restrict__ rp,
                                                 const int* __restrict__ col,
                                                 const float* __restrict__ dis,
                                                 const float* __restrict__ bias,
                                                 ushort* __restrict__ act,
                                                 float* __restrict__ out,
                                                 const int* __restrict__ ovf,
                                                 const int* __restrict__ ovf_cnt) {
    int cnt = *ovf_cnt; if (cnt > OVF_CAP) cnt = OVF_CAP;
    int wid = threadIdx.x >> 6, lane = threadIdx.x & 63;
    int g = lane >> 4, cl = lane & 15;
    const char* base = (const char*)hs + (cl << 4);
    for (int i = wid; i < cnt; i += 4) {
        int node = ovf[i];
        float ax[8];
#pragma unroll
        for (int j = 0; j < 8; ++j) ax[j] = 0.f;
        int beg = rp[node], end = rp[node + 1];
        for (int e = beg; e < end; e += 4) {
            int idx = e + g;
            int s = (idx < end) ? col[idx] : PAD_V;
            uint4 u = *(const uint4*)(base + (size_t)(uint)s);
            ax[0] += bf_lo(u.x); ax[1] += bf_hi(u.x);
            ax[2] += bf_lo(u.y); ax[3] += bf_hi(u.y);
            ax[4] += bf_lo(u.z); ax[5] += bf_hi(u.z);
            ax[6] += bf_lo(u.w); ax[7] += bf_hi(u.w);
        }
#pragma unroll
        for (int j = 0; j < 8; ++j) {
            ax[j] += __shfl_xor(ax[j], 16);
            ax[j] += __shfl_xor(ax[j], 32);
        }
        if (g == 0) {
            float dn = dis[node];
            uint4 un = *(const uint4*)(base + ((size_t)node << 8));
            float hsn[8] = {bf_lo(un.x), bf_hi(un.x), bf_lo(un.y), bf_hi(un.y),
                            bf_lo(un.z), bf_hi(un.z), bf_lo(un.w), bf_hi(un.w)};
            int c0 = cl * 8;
            float4 bv0 = *(const float4*)&bias[c0];
            float4 bv1 = *(const float4*)&bias[c0 + 4];
            float bb[8] = {bv0.x, bv0.y, bv0.z, bv0.w, bv1.x, bv1.y, bv1.z, bv1.w};
            float o[8];
#pragma unroll
            for (int j = 0; j < 8; ++j)
                o[j] = fmaxf((ax[j] + hsn[j]) * dn + bb[j], 0.f);
            if (LAST) {
                *(float4*)&out[(size_t)node * D_HID + c0]     = make_float4(o[0], o[1], o[2], o[3]);
                *(float4*)&out[(size_t)node * D_HID + c0 + 4] = make_float4(o[4], o[5], o[6], o[7]);
            } else {
                uint4 p;
                p.x = (uint)f2bf(o[0]) | ((uint)f2bf(o[1]) << 16);
                p.y = (uint)f2bf(o[2]) | ((uint)f2bf(o[3]) << 16);
                p.z = (uint)f2bf(o[4]) | ((uint)f2bf(o[5]) << 16);
                p.w = (uint)f2bf(o[6]) | ((uint)f2bf(o[7]) << 16);
                *(uint4*)((char*)act + ((size_t)node << 8) + (cl << 4)) = p;
            }
        }
    }
}

extern "C" void kernel_launch(void* const* d_in, const int* in_sizes, int n_in,
                              void* d_out, int out_size, void* d_ws, size_t ws_size,
                              hipStream_t stream) {
    const float* x  = (const float*)d_in[0];
    const int*   ei = (const int*)d_in[1];
    const float* W0 = (const float*)d_in[2];
    const float* b0 = (const float*)d_in[3];
    const float* W1 = (const float*)d_in[4];
    const float* b1 = (const float*)d_in[5];
    const float* W2 = (const float*)d_in[6];
    const float* b2 = (const float*)d_in[7];
    float* out = (float*)d_out;

    const int N = N_NODES, E = N_EDGES;
    const int* src = ei;
    const int* dst = ei + E;

    char* w = (char*)d_ws;
    size_t off = 0;
    auto alloc = [&](size_t bytes) {
        size_t o = off;
        off += (bytes + 255) & ~(size_t)255;
        return o;
    };
    int*    bcur   = (int*)(w + alloc((size_t)(NB + 1) * 4));   // [NB]=ovf_cnt
    int*    ovf    = (int*)(w + alloc((size_t)OVF_CAP * 4));
    float*  dis    = (float*)(w + alloc((size_t)N * 4));
    int*    rp     = (int*)(w + alloc((size_t)(N + 1) * 4));
    int*    boff   = (int*)(w + alloc((size_t)NB * 4));
    int*    col    = (int*)(w + alloc((size_t)E * 4));
    int*    col32  = (int*)(w + alloc((size_t)N * 32 * 4));
    int2*   ebuf   = (int2*)(w + alloc((size_t)NB * CAP * 8));
    ushort* hb     = (ushort*)(w + alloc((size_t)(N + 1) * D_HID * 2));  // +1 zero pad row
    ushort* act    = (ushort*)(w + alloc((size_t)N * D_HID * 2));
    ushort* Wt0    = (ushort*)(w + alloc((size_t)128 * 256 * 2));
    ushort* Wt1    = (ushort*)(w + alloc((size_t)128 * 128 * 2));
    ushort* Wt2    = (ushort*)(w + alloc((size_t)128 * 128 * 2));
    int*    ovf_cnt = bcur + NB;
    (void)ws_size; (void)n_in; (void)in_sizes; (void)out_size;

    hipMemsetAsync(bcur, 0, (size_t)(NB + 1) * 4, stream);

    part_k<<<P1_BLOCKS, 256, 0, stream>>>(src, dst, bcur, ebuf, E);
    bscan196_k<<<1, 256, 0, stream>>>(bcur, boff, rp + N);
    csr2_k<<<NB, 256, 0, stream>>>(ebuf, bcur, boff, rp, dis, col, col32, ovf, ovf_cnt, N);
    int srt_blocks = (N + 7) / 8;   // 6250
    rowsort32_k<<<srt_blocks + 1, 256, 0, stream>>>(col32, rp, col, ovf, ovf_cnt, N, srt_blocks);

    wtrans_all_k<<<256, 256, 0, stream>>>(W0, W1, W2, Wt0, Wt1, Wt2,
                                          (uint*)(hb + (size_t)N * D_HID));

    int g32 = (N + 31) / 32;    // 1563 (layer 0, 32-row tiles)
    int g64 = (N + 63) / 64;    // 782  (layers 1-2, 64-row tiles)
    int halfG = N / 4;          // 12500 blocks per column half
    int agg_grid = 2 * halfG;

    // layer 0
    gemm_lds_k<256, 32, true><<<g32, 256, 0, stream>>>(x, Wt0, dis, hb, N);
    aggregate_k<false><<<agg_grid, 256, 0, stream>>>(hb, col32, dis, b0, act, out, halfG);
    ovf_agg_k<false><<<1, 256, 0, stream>>>(hb, rp, col, dis, b0, act, out, ovf, ovf_cnt);
    // layer 1
    gemm_lds_k<128, 64, false><<<g64, 256, 0, stream>>>(act, Wt1, dis, hb, N);
    aggregate_k<false><<<agg_grid, 256, 0, stream>>>(hb, col32, dis, b1, act, out, halfG);
    ovf_agg_k<false><<<1, 256, 0, stream>>>(hb, rp, col, dis, b1, act, out, ovf, ovf_cnt);
    // layer 2
    gemm_lds_k<128, 64, false><<<g64, 256, 0, stream>>>(act, Wt2, dis, hb, N);
    aggregate_k<true><<<agg_grid, 256, 0, stream>>>(hb, col32, dis, b2, act, out, halfG);
    ovf_agg_k<true><<<1, 256, 0, stream>>>(hb, rp, col, dis, b2, act, out, ovf, ovf_cnt);
}

// Round 17
// 229.846 us; speedup vs baseline: 1.4433x; 1.1168x over previous
//
#include <hip/hip_runtime.h>

#define N_NODES 50000
#define N_EDGES 800000
#define D_HID   128

typedef unsigned int uint;
typedef unsigned short ushort;
typedef __attribute__((ext_vector_type(8))) short short8;
typedef __attribute__((ext_vector_type(4))) float f32x4;

#define NB       196                       // dst buckets of 256 nodes
#define CAP      6144                      // per-bucket ebuf capacity
#define P1_BLOCKS 200
#define P1_CHUNK  4000                     // 200 * 4000 = 800000 exactly

// ---------------- P1: partition edges into dst-range buckets ----------------
__global__ __launch_bounds__(256) void part_k(const int* __restrict__ src,
                                              const int* __restrict__ dst,
                                              int* __restrict__ bcur,
                                              int2* __restrict__ ebuf, int e) {
    __shared__ int hist[NB];
    __shared__ int base[NB];
    int tid = threadIdx.x;
    if (tid < NB) hist[tid] = 0;
    __syncthreads();

    int e0 = blockIdx.x * P1_CHUNK;
    int2 ed[16];
    bool val[16];
#pragma unroll
    for (int i = 0; i < 16; ++i) {
        int o = i * 256 + tid;
        int idx = e0 + o;
        val[i] = (o < P1_CHUNK) && (idx < e);
        if (val[i]) {
            ed[i] = make_int2(src[idx], dst[idx]);
            atomicAdd(&hist[ed[i].y >> 8], 1);
        }
    }
    __syncthreads();
    if (tid < NB && hist[tid] > 0) base[tid] = atomicAdd(&bcur[tid], hist[tid]);
    __syncthreads();
    if (tid < NB) hist[tid] = 0;
    __syncthreads();
#pragma unroll
    for (int i = 0; i < 16; ++i) {
        if (val[i]) {
            int bk = ed[i].y >> 8;
            int o  = base[bk] + atomicAdd(&hist[bk], 1);
            if (o < CAP) ebuf[(size_t)bk * CAP + o] = ed[i];
        }
    }
}

// ---------------- scan of per-bucket totals (bcur) -> boff, row_ptr[N] ----------------
__global__ void bscan196_k(const int* __restrict__ bcur, int* __restrict__ boff,
                           int* __restrict__ row_ptr_end) {
    __shared__ int s[256];
    int t = threadIdx.x;
    int v = (t < NB) ? bcur[t] : 0;
    s[t] = v;
    __syncthreads();
    for (int off = 1; off < 256; off <<= 1) {
        int u = (t >= off) ? s[t - off] : 0;
        __syncthreads();
        s[t] += u;
        __syncthreads();
    }
    if (t < NB) boff[t] = s[t] - v;        // exclusive
    if (t == 255) *row_ptr_end = s[255];   // total -> row_ptr[n]
}

// ---------------- per-bucket count + LDS scan -> row_ptr + dis ----------------
__global__ __launch_bounds__(256) void cntscan_k(const int2* __restrict__ ebuf,
                                                 const int* __restrict__ bcnt,
                                                 const int* __restrict__ boff,
                                                 int* __restrict__ row_ptr,
                                                 float* __restrict__ dis, int n) {
    __shared__ int c[256];
    __shared__ int s[256];
    int b = blockIdx.x, tid = threadIdx.x;
    c[tid] = 0;
    __syncthreads();
    int m = bcnt[b]; if (m > CAP) m = CAP;
    for (int i = tid; i < m; i += 256)
        atomicAdd(&c[ebuf[(size_t)b * CAP + i].y & 255], 1);
    __syncthreads();
    int v = c[tid];
    s[tid] = v;
    __syncthreads();
    for (int off = 1; off < 256; off <<= 1) {
        int u = (tid >= off) ? s[tid - off] : 0;
        __syncthreads();
        s[tid] += u;
        __syncthreads();
    }
    int node = b * 256 + tid;
    if (node < n) {
        row_ptr[node] = boff[b] + s[tid] - v;
        dis[node] = rsqrtf((float)v + 1.0f);
    }
}

// ---------------- P3: per-bucket CSR scatter via LDS window (coalesced dump) ----------------
// stores src<<8 (pre-shifted byte offsets for the aggregate's gathers)
__global__ __launch_bounds__(256) void csr_k(const int2* __restrict__ ebuf,
                                             const int* __restrict__ bcnt,
                                             const int* __restrict__ row_ptr,
                                             int* __restrict__ col, int n) {
    __shared__ int rp_l[257];
    __shared__ int cur[256];
    __shared__ int win[CAP];
    int b = blockIdx.x, tid = threadIdx.x;
    int node0 = b * 256;
    for (int i = tid; i < 257; i += 256) {
        int nd = node0 + i; if (nd > n) nd = n;
        rp_l[i] = row_ptr[nd];
    }
    cur[tid] = 0;
    __syncthreads();
    int base0 = rp_l[0];
    int m = bcnt[b]; if (m > CAP) m = CAP;

    for (int i = tid; i < m; i += 256) {
        int2 ed = ebuf[(size_t)b * CAP + i];
        int ll = ed.y & 255;
        int pos = rp_l[ll] + atomicAdd(&cur[ll], 1) - base0;
        win[pos] = ed.x << 8;                       // pre-shifted
    }
    __syncthreads();
    for (int i = tid; i < m; i += 256) col[base0 + i] = win[i];
}

// ---------------- canonicalize: wave-per-row sort (wide grid) ----------------
__global__ __launch_bounds__(256) void rowsort_k(const int* __restrict__ rp,
                                                 int* __restrict__ col, int n) {
    int node = blockIdx.x * 4 + (threadIdx.x >> 6);
    if (node >= n) return;
    int lane = threadIdx.x & 63;
    int beg = rp[node], end = rp[node + 1];
    int len = end - beg;
    if (len <= 1) return;
    if (len <= 64) {
        int v = (lane < len) ? col[beg + lane] : 0x7fffffff;
#pragma unroll
        for (int k = 2; k <= 64; k <<= 1)
#pragma unroll
            for (int j = k >> 1; j > 0; j >>= 1) {
                int other = __shfl_xor(v, j);
                bool up    = (lane & k) == 0;
                bool small = (lane & j) == 0;
                v = (small == up) ? min(v, other) : max(v, other);
            }
        if (lane < len) col[beg + lane] = v;
    } else if (lane == 0) {     // rare tail: serial insertion sort
        for (int i = beg + 1; i < end; ++i) {
            int key = col[i]; int j = i - 1;
            while (j >= beg && col[j] > key) { col[j + 1] = col[j]; --j; }
            col[j + 1] = key;
        }
    }
}

// ---- fp32 -> bf16 (RTNE) ----
__device__ inline ushort f2bf(float f) {
    unsigned u = __float_as_uint(f);
    unsigned rounding = 0x7fffu + ((u >> 16) & 1u);
    return (ushort)((u + rounding) >> 16);
}
__device__ inline float bf_lo(uint v) { return __uint_as_float(v << 16); }
__device__ inline float bf_hi(uint v) { return __uint_as_float(v & 0xffff0000u); }
__device__ inline short8 cvt8(float4 f0, float4 f1) {
    short8 r;
    r[0] = (short)f2bf(f0.x); r[1] = (short)f2bf(f0.y);
    r[2] = (short)f2bf(f0.z); r[3] = (short)f2bf(f0.w);
    r[4] = (short)f2bf(f1.x); r[5] = (short)f2bf(f1.y);
    r[6] = (short)f2bf(f1.z); r[7] = (short)f2bf(f1.w);
    return r;
}

// async global -> LDS (16B per lane; LDS dest = wave-uniform base + lane*16)
__device__ inline void gload16(const void* g, void* l) {
    __builtin_amdgcn_global_load_lds(
        (const __attribute__((address_space(1))) uint*)g,
        (__attribute__((address_space(3))) uint*)l, 16, 0, 0);
}

// ---------------- all three W -> Wt bf16, one launch; also zero hb pad row N ----------------
__global__ void wtrans_all_k(const float* __restrict__ W0, const float* __restrict__ W1,
                             const float* __restrict__ W2, ushort* __restrict__ Wt0,
                             ushort* __restrict__ Wt1, ushort* __restrict__ Wt2,
                             uint* __restrict__ hb_padrow) {
    int i = blockIdx.x * 256 + threadIdx.x;   // 0..65535
    if (i < 64) hb_padrow[i] = 0;             // zero row N of hb (gather target for pad slots)
    const float* W; ushort* Wt; int K, j;
    if (i < 32768)      { W = W0; Wt = Wt0; K = 256; j = i; }
    else if (i < 49152) { W = W1; Wt = Wt1; K = 128; j = i - 32768; }
    else                { W = W2; Wt = Wt2; K = 128; j = i - 49152; }
    int k = j >> 7, n = j & 127;
    Wt[(size_t)n * K + k] = f2bf(W[j]);
}

// ---------------- MFMA GEMM: global_load_lds staged A tile, register-resident B ----------------
// LDS layout is LINEAR; the XOR-swizzle is applied to the GLOBAL source address
// (LDS slot [row][cb] holds A[row][cb ^ (row&7)]), so the ds_read side is
// bank-conflict-free and gload_lds's uniform-base+lane*16 constraint is met.
// 4 waves, wave w owns cols w*32..w*32+31. Epilogue: H = dis * (A W) in bf16.
template<int K, int ROWS, bool AF32>
__global__ __launch_bounds__(256) void gemm_lds_k(const void* __restrict__ Ap,
                                                  const ushort* __restrict__ Bt, // [128][K]
                                                  const float* __restrict__ dis,
                                                  ushort* __restrict__ H,        // [(M+1)][128]
                                                  int M) {
    constexpr int T  = K / 32;                 // MFMA k-steps
    constexpr int EB = AF32 ? 4 : 2;           // element bytes
    constexpr int RS = K * EB;                 // row stride bytes
    constexpr int NI = (ROWS * RS) / 4096;     // staging iters (4 waves x 1KB)
    __shared__ char As[ROWS * RS];

    int tid = threadIdx.x;
    int w = tid >> 6, l = tid & 63, lr = l & 15, hi = l >> 4;
    int cBase = w * 32;

    // B-fragments register-resident (2 col-blocks x T)
    short8 b[2][T];
#pragma unroll
    for (int c = 0; c < 2; ++c)
#pragma unroll
        for (int t = 0; t < T; ++t)
            b[c][t] = *(const short8*)&Bt[(size_t)(cBase + c * 16 + lr) * K + t * 32 + hi * 8];

    int r0 = blockIdx.x * ROWS;
    const char* gbase = (const char*)Ap + (size_t)r0 * RS;

    // stage A tile: pre-swizzled global source -> linear LDS via global_load_lds
#pragma unroll
    for (int i = 0; i < NI; ++i) {
        int L0  = (i * 4 + w) * 1024;          // wave-uniform LDS base
        int L   = L0 + l * 16;
        int row = L / RS;
        int cb  = (L % RS) >> 4;
        int gb  = (cb ^ (row & 7)) << 4;
        int grow = (r0 + row < M) ? row : 0;   // tail clamp (masked at store)
        gload16(gbase + (size_t)grow * RS + gb, &As[L0]);
    }
    __syncthreads();

    f32x4 acc[ROWS / 16][2];
#pragma unroll
    for (int rb = 0; rb < ROWS / 16; ++rb)
#pragma unroll
        for (int c = 0; c < 2; ++c) acc[rb][c] = (f32x4){0.f, 0.f, 0.f, 0.f};

#pragma unroll
    for (int rb = 0; rb < ROWS / 16; ++rb) {
        int row = rb * 16 + lr;
        int s = row & 7;
        const char* rbase = &As[row * RS];
#pragma unroll
        for (int t = 0; t < T; ++t) {
            short8 a;
            if constexpr (AF32) {
                int cb0 = t * 8 + hi * 2;
                float4 f0 = *(const float4*)(rbase + ((cb0 ^ s) << 4));
                float4 f1 = *(const float4*)(rbase + (((cb0 + 1) ^ s) << 4));
                a = cvt8(f0, f1);
            } else {
                int cb0 = t * 4 + hi;
                a = *(const short8*)(rbase + ((cb0 ^ s) << 4));
            }
#pragma unroll
            for (int c = 0; c < 2; ++c)
                acc[rb][c] = __builtin_amdgcn_mfma_f32_16x16x32_bf16(a, b[c][t], acc[rb][c], 0, 0, 0);
        }
    }

    // epilogue: dis-scale + bf16 store
#pragma unroll
    for (int rb = 0; rb < ROWS / 16; ++rb) {
#pragma unroll
        for (int j = 0; j < 4; ++j) {
            int r = r0 + rb * 16 + hi * 4 + j;
            if (r < M) {
                float d = dis[r];
#pragma unroll
                for (int c = 0; c < 2; ++c)
                    H[(size_t)r * 128 + cBase + c * 16 + lr] = f2bf(acc[rb][c][j] * d);
            }
        }
    }
}

// ---------------- aggregate: relu(dis[n]*(sum_e hs[s] + hs[n]) + b) ----------------
// hs pre-scaled by dis in the GEMM epilogue; col holds pre-shifted byte offsets;
// pad slots gather the zero row N. 8 slots x 4 lane-groups = 32 edges in flight.
template<bool LAST>
__global__ __launch_bounds__(256) void aggregate_k(const ushort* __restrict__ hs,
                                                   const int* __restrict__ row_ptr,
                                                   const int* __restrict__ col,
                                                   const float* __restrict__ dis,
                                                   const float* __restrict__ bias,
                                                   ushort* __restrict__ act,
                                                   float* __restrict__ out, int n) {
    int node = blockIdx.x * 4 + (threadIdx.x >> 6);
    if (node >= n) return;
    int lane = threadIdx.x & 63;
    int g  = lane >> 4;          // edge-slot group 0..3
    int cl = lane & 15;          // column block: cols [8*cl, 8*cl+8)
    const char* base = (const char*)hs + (cl << 4);

    float ax[8];
#pragma unroll
    for (int j = 0; j < 8; ++j) ax[j] = 0.f;

    int beg = row_ptr[node], end = row_ptr[node + 1];
    for (int e = beg; e < end; e += 32) {
        int s[8];
#pragma unroll
        for (int q = 0; q < 8; ++q) {
            int idx = e + q * 4 + g;
            s[q] = (idx < end) ? col[idx] : (N_NODES << 8);   // pad -> zero row
        }
        uint4 u[8];
#pragma unroll
        for (int q = 0; q < 8; ++q)
            u[q] = *(const uint4*)(base + (size_t)(uint)s[q]);
#pragma unroll
        for (int q = 0; q < 8; ++q) {
            ax[0] += bf_lo(u[q].x); ax[1] += bf_hi(u[q].x);
            ax[2] += bf_lo(u[q].y); ax[3] += bf_hi(u[q].y);
            ax[4] += bf_lo(u[q].z); ax[5] += bf_hi(u[q].z);
            ax[6] += bf_lo(u[q].w); ax[7] += bf_hi(u[q].w);
        }
    }
#pragma unroll
    for (int j = 0; j < 8; ++j) {
        ax[j] += __shfl_xor(ax[j], 16);
        ax[j] += __shfl_xor(ax[j], 32);
    }
    if (g == 0) {
        float dn = dis[node];
        uint4 un = *(const uint4*)(base + ((size_t)node << 8));
        float hsn[8] = {bf_lo(un.x), bf_hi(un.x), bf_lo(un.y), bf_hi(un.y),
                        bf_lo(un.z), bf_hi(un.z), bf_lo(un.w), bf_hi(un.w)};
        int c0 = cl * 8;
        float4 bv0 = *(const float4*)&bias[c0];
        float4 bv1 = *(const float4*)&bias[c0 + 4];
        float bb[8] = {bv0.x, bv0.y, bv0.z, bv0.w, bv1.x, bv1.y, bv1.z, bv1.w};
        float o[8];
#pragma unroll
        for (int j = 0; j < 8; ++j)
            o[j] = fmaxf((ax[j] + hsn[j]) * dn + bb[j], 0.f);
        if (LAST) {
            *(float4*)&out[(size_t)node * D_HID + c0]     = make_float4(o[0], o[1], o[2], o[3]);
            *(float4*)&out[(size_t)node * D_HID + c0 + 4] = make_float4(o[4], o[5], o[6], o[7]);
        } else {
            uint4 p;
            p.x = (uint)f2bf(o[0]) | ((uint)f2bf(o[1]) << 16);
            p.y = (uint)f2bf(o[2]) | ((uint)f2bf(o[3]) << 16);
            p.z = (uint)f2bf(o[4]) | ((uint)f2bf(o[5]) << 16);
            p.w = (uint)f2bf(o[6]) | ((uint)f2bf(o[7]) << 16);
            *(uint4*)((char*)act + ((size_t)node << 8) + (cl << 4)) = p;
        }
    }
}

extern "C" void kernel_launch(void* const* d_in, const int* in_sizes, int n_in,
                              void* d_out, int out_size, void* d_ws, size_t ws_size,
                              hipStream_t stream) {
    const float* x  = (const float*)d_in[0];
    const int*   ei = (const int*)d_in[1];
    const float* W0 = (const float*)d_in[2];
    const float* b0 = (const float*)d_in[3];
    const float* W1 = (const float*)d_in[4];
    const float* b1 = (const float*)d_in[5];
    const float* W2 = (const float*)d_in[6];
    const float* b2 = (const float*)d_in[7];
    float* out = (float*)d_out;

    const int N = N_NODES, E = N_EDGES;
    const int* src = ei;
    const int* dst = ei + E;

    char* w = (char*)d_ws;
    size_t off = 0;
    auto alloc = [&](size_t bytes) {
        size_t o = off;
        off += (bytes + 255) & ~(size_t)255;
        return o;
    };
    int*    bcur   = (int*)(w + alloc((size_t)NB * 4));
    float*  dis    = (float*)(w + alloc((size_t)N * 4));
    int*    rp     = (int*)(w + alloc((size_t)(N + 1) * 4));
    int*    boff   = (int*)(w + alloc((size_t)NB * 4));
    int*    col    = (int*)(w + alloc((size_t)E * 4));
    int2*   ebuf   = (int2*)(w + alloc((size_t)NB * CAP * 8));
    ushort* hb     = (ushort*)(w + alloc((size_t)(N + 1) * D_HID * 2));  // +1 zero pad row
    ushort* act    = (ushort*)(w + alloc((size_t)N * D_HID * 2));
    ushort* Wt0    = (ushort*)(w + alloc((size_t)128 * 256 * 2));
    ushort* Wt1    = (ushort*)(w + alloc((size_t)128 * 128 * 2));
    ushort* Wt2    = (ushort*)(w + alloc((size_t)128 * 128 * 2));
    (void)ws_size; (void)n_in; (void)in_sizes; (void)out_size;

    hipMemsetAsync(bcur, 0, (size_t)NB * 4, stream);

    part_k<<<P1_BLOCKS, 256, 0, stream>>>(src, dst, bcur, ebuf, E);
    bscan196_k<<<1, 256, 0, stream>>>(bcur, boff, rp + N);
    cntscan_k<<<NB, 256, 0, stream>>>(ebuf, bcur, boff, rp, dis, N);
    csr_k<<<NB, 256, 0, stream>>>(ebuf, bcur, rp, col, N);
    rowsort_k<<<(N + 3) / 4, 256, 0, stream>>>(rp, col, N);   // canonical order

    wtrans_all_k<<<256, 256, 0, stream>>>(W0, W1, W2, Wt0, Wt1, Wt2,
                                          (uint*)(hb + (size_t)N * D_HID));

    int g32 = (N + 31) / 32;    // 1563 (layer 0, 32-row tiles)
    int g64 = (N + 63) / 64;    // 782  (layers 1-2, 64-row tiles)
    int agg_grid = (N + 3) / 4;

    // layer 0
    gemm_lds_k<256, 32, true><<<g32, 256, 0, stream>>>(x, Wt0, dis, hb, N);
    aggregate_k<false><<<agg_grid, 256, 0, stream>>>(hb, rp, col, dis, b0, act, out, N);
    // layer 1
    gemm_lds_k<128, 64, false><<<g64, 256, 0, stream>>>(act, Wt1, dis, hb, N);
    aggregate_k<false><<<agg_grid, 256, 0, stream>>>(hb, rp, col, dis, b1, act, out, N);
    // layer 2
    gemm_lds_k<128, 64, false><<<g64, 256, 0, stream>>>(act, Wt2, dis, hb, N);
    aggregate_k<true><<<agg_grid, 256, 0, stream>>>(hb, rp, col, dis, b2, act, out, N);
}